// Round 5
// baseline (284.227 us; speedup 1.0000x reference)
//
#include <hip/hip_runtime.h>
#include <hip/hip_bf16.h>
#include <stdint.h>

#define BATCH 8192
#define GROWS 9216          // >= 8192 + 7*127 padded rows
#define DIN   2048
#define DOUT  2048
#define NEXP  8
#define BM    128
#define BN    256
#define BK    32
#define NT    (DIN / BK)    // 64 K-tiles
#define NSLOT 72
// LDS: A slots 4 x 8192 at 0; B slots 3 x 16384 at 32768; total 81920 (2 blocks/CU)
#define AB0 0
#define AB1 8192
#define AB2 16384
#define AB3 24576
#define BB0 32768
#define BB1 49152
#define BB2 65536

typedef __attribute__((ext_vector_type(4))) float fx4;
typedef __attribute__((ext_vector_type(8))) short sx8;

__device__ __forceinline__ short f2b(float x){
  unsigned u = __float_as_uint(x);
  u = u + 0x7FFFu + ((u >> 16) & 1u);   // round-to-nearest-even
  return (short)(u >> 16);
}

__device__ __forceinline__ void gload16(const void* g, void* l){
  __builtin_amdgcn_global_load_lds(
      (const __attribute__((address_space(1))) unsigned int*)g,
      (__attribute__((address_space(3))) unsigned int*)l, 16, 0, 0);
}

// ---- pass 1: counts, offsets, slot->expert LUT, perm = -1 ----
__global__ void prep_count(const int* __restrict__ actions, int* __restrict__ perm,
                           int* __restrict__ meta){
  __shared__ int cnt[NEXP];
  int t = threadIdx.x;   // 1024
  if (t < NEXP) cnt[t] = 0;
  for (int i = t; i < GROWS; i += 1024) perm[i] = -1;
  __syncthreads();
  for (int i = t; i < BATCH; i += 1024) atomicAdd(&cnt[actions[i]], 1);
  __syncthreads();
  if (t == 0){
    int s = 0, slot = 0;
    for (int e = 0; e < NEXP; ++e){
      meta[e] = s;                          // running scatter cursor (global)
      int ns = (cnt[e] + BM - 1) / BM;
      for (int q = 0; q < ns; ++q) meta[17 + slot++] = e;
      s += ns * BM;
    }
    meta[16] = slot;
  }
}

// ---- pass 2: scatter perm (32 blocks) + metadata tail ----
__global__ void prep_scatter(const int* __restrict__ actions, const int* __restrict__ mxs,
                             int* __restrict__ perm, int* __restrict__ meta,
                             float* __restrict__ out){
  int i = blockIdx.x * 256 + threadIdx.x;
  if (i < BATCH){
    int e = actions[i];
    int p = atomicAdd(&meta[e], 1);
    perm[p] = i;
    out[(size_t)BATCH * DOUT + i]         = (float)mxs[i];
    out[(size_t)BATCH * DOUT + BATCH + i] = (float)actions[i];
  }
}

// ---- gather + convert: xp[i][k] = bf16(xs[perm[i]][k]); pad rows -> 0 ----
__global__ void gatherx_kernel(const float* __restrict__ xs, const int* __restrict__ perm,
                               short* __restrict__ xp){
  int i = blockIdx.x;
  int t = threadIdx.x;
  short v[8];
  int p = perm[i];
  if (p >= 0){
    const fx4* src = (const fx4*)(xs + (size_t)p * DIN + t * 8);
    fx4 a = src[0], b2 = src[1];
    v[0]=f2b(a.x); v[1]=f2b(a.y); v[2]=f2b(a.z); v[3]=f2b(a.w);
    v[4]=f2b(b2.x); v[5]=f2b(b2.y); v[6]=f2b(b2.z); v[7]=f2b(b2.w);
  } else {
#pragma unroll
    for (int j = 0; j < 8; ++j) v[j] = 0;
  }
  *(sx8*)(xp + (size_t)i * DIN + t * 8) = *(const sx8*)v;
}

// ---- W[e][k][n] f32 -> Wt[e][n][k] bf16 ----
__global__ void transw_kernel(const float* __restrict__ W, short* __restrict__ Wt){
  __shared__ float tile[64][69];
  int e  = blockIdx.z;
  int n0 = blockIdx.x * 64;
  int k0 = blockIdx.y * 64;
  const float* Wp = W + (size_t)e * DIN * DOUT + (size_t)k0 * DOUT + n0;
  int t = threadIdx.x;   // 256
#pragma unroll
  for (int it = 0; it < 4; ++it){
    int r = it * 16 + (t >> 4);
    int c = (t & 15) * 4;
    fx4 v = *(const fx4*)(Wp + (size_t)r * DOUT + c);
    tile[r][c] = v.x; tile[r][c+1] = v.y; tile[r][c+2] = v.z; tile[r][c+3] = v.w;
  }
  __syncthreads();
  int n  = t >> 2;
  int kc = (t & 3) * 16;
  short vv[16];
#pragma unroll
  for (int j = 0; j < 16; ++j) vv[j] = f2b(tile[kc + j][n]);
  short* dst = Wt + (size_t)e * DOUT * DIN + (size_t)(n0 + n) * DIN + k0 + kc;
  *(sx8*)dst       = *(const sx8*)vv;
  *(sx8*)(dst + 8) = *(const sx8*)(vv + 8);
}

// ---- grouped GEMM: 128x256xBK32, A-depth4/B-depth3 pipeline, vmcnt(4), 1 barrier/step ----
__global__ __launch_bounds__(512, 4)
void moe_gemm_kernel(const short* __restrict__ xp, const short* __restrict__ Wt,
                     const float* __restrict__ bias, const int* __restrict__ perm,
                     const int* __restrict__ meta, float* __restrict__ out){
  __shared__ char lds[81920];

  int F = blockIdx.x;               // slot*8 + nb : XCD = F%8 = nb (B L2-reuse)
  int slot = F >> 3, nb = F & 7;
  if (slot >= meta[16]) return;
  int e      = meta[17 + slot];
  int m_base = slot * BM;
  int n0     = nb * BN;

  int t    = threadIdx.x;
  int wid  = t >> 6;
  int l    = t & 63;
  int wm   = wid & 1;               // 2 wave rows
  int wn   = wid >> 1;              // 4 wave cols
  int lrow = l & 15;
  int lk   = l >> 4;

  // staging sources: LDS pos t*16 <-> [kchunk][row] layout
  const char* ag = (const char*)xp + ((size_t)(m_base + (t & 127)) * DIN + (t >> 7) * 8) * 2;
  const char* bg = (const char*)Wt + (((size_t)e * DOUT + n0 + (t & 255)) * DIN + (t >> 8) * 8) * 2;

  // fragment read addrs (within slot): [lk][row][16B] -> conflict-free
  int addrA = lk * 2048 + (wm * 64 + lrow) * 16;
  int addrB = lk * 4096 + (wn * 64 + lrow) * 16;

  fx4 acc[4][4];
#pragma unroll
  for (int m = 0; m < 4; ++m)
#pragma unroll
    for (int n = 0; n < 4; ++n)
      acc[m][n] = (fx4){0.f, 0.f, 0.f, 0.f};

  float bcol[4];
#pragma unroll
  for (int n = 0; n < 4; ++n)
    bcol[n] = bias[(size_t)e * DOUT + n0 + wn * 64 + n * 16 + lrow];

#define STGA(KT, SA) gload16(ag + (size_t)(KT) * 64, lds + (SA) + (t << 4))
#define STGB(KT, SB) do{ gload16(bg + (size_t)(KT) * 64,      lds + (SB) + (t << 4)); \
                         gload16(bg + (size_t)(KT) * 64 + 32, lds + (SB) + 8192 + (t << 4)); }while(0)

#define KSTEP(CA, CB, SA, SB, KT, DOB, DOA, VM) do{ \
    if (DOB) STGB((KT) + 2, SB); \
    if (DOA) STGA((KT) + 3, SA); \
    sx8 af[4], bf[4]; \
    _Pragma("unroll") for (int m = 0; m < 4; ++m) \
      af[m] = *(const sx8*)(lds + (CA) + addrA + m * 256); \
    _Pragma("unroll") for (int n = 0; n < 4; ++n) \
      bf[n] = *(const sx8*)(lds + (CB) + addrB + n * 256); \
    __builtin_amdgcn_s_setprio(1); \
    _Pragma("unroll") for (int m = 0; m < 4; ++m) \
    _Pragma("unroll") for (int n = 0; n < 4; ++n) \
      acc[m][n] = __builtin_amdgcn_mfma_f32_16x16x32_bf16(af[m], bf[n], acc[m][n], 0, 0, 0); \
    __builtin_amdgcn_s_setprio(0); \
    asm volatile("s_waitcnt vmcnt(" #VM ")" ::: "memory"); \
    __builtin_amdgcn_s_barrier(); \
    asm volatile("" ::: "memory"); \
  }while(0)

  // prologue: A0,B0,A1,B1,A2 staged; wait A0,B0
  STGA(0, AB0); STGB(0, BB0);
  STGA(1, AB1); STGB(1, BB1);
  STGA(2, AB2);
  asm volatile("s_waitcnt vmcnt(4)" ::: "memory");
  __builtin_amdgcn_s_barrier();
  asm volatile("" ::: "memory");

  for (int kt = 0; kt < 60; kt += 12){
    KSTEP(AB0, BB0, AB3, BB2, kt + 0,  1, 1, 4);
    KSTEP(AB1, BB1, AB0, BB0, kt + 1,  1, 1, 4);
    KSTEP(AB2, BB2, AB1, BB1, kt + 2,  1, 1, 4);
    KSTEP(AB3, BB0, AB2, BB2, kt + 3,  1, 1, 4);
    KSTEP(AB0, BB1, AB3, BB0, kt + 4,  1, 1, 4);
    KSTEP(AB1, BB2, AB0, BB1, kt + 5,  1, 1, 4);
    KSTEP(AB2, BB0, AB1, BB2, kt + 6,  1, 1, 4);
    KSTEP(AB3, BB1, AB2, BB0, kt + 7,  1, 1, 4);
    KSTEP(AB0, BB2, AB3, BB1, kt + 8,  1, 1, 4);
    KSTEP(AB1, BB0, AB0, BB2, kt + 9,  1, 1, 4);
    KSTEP(AB2, BB1, AB1, BB0, kt + 10, 1, 1, 4);
    KSTEP(AB3, BB2, AB2, BB1, kt + 11, 1, 1, 4);
  }
  KSTEP(AB0, BB0, AB3, BB2, 60, 1, 1, 4);
  KSTEP(AB1, BB1, AB0, BB0, 61, 1, 0, 3);   // stages B63 -> BB0
  KSTEP(AB2, BB2, AB0, BB0, 62, 0, 0, 0);
  // step 63: compute only, no stage/wait/barrier
  {
    sx8 af[4], bf[4];
#pragma unroll
    for (int m = 0; m < 4; ++m) af[m] = *(const sx8*)(lds + AB3 + addrA + m * 256);
#pragma unroll
    for (int n = 0; n < 4; ++n) bf[n] = *(const sx8*)(lds + BB0 + addrB + n * 256);
#pragma unroll
    for (int m = 0; m < 4; ++m)
#pragma unroll
      for (int n = 0; n < 4; ++n)
        acc[m][n] = __builtin_amdgcn_mfma_f32_16x16x32_bf16(af[m], bf[n], acc[m][n], 0, 0, 0);
  }

  // epilogue: scatter rows via perm, add bias
#pragma unroll
  for (int m = 0; m < 4; ++m){
    int rb = wm * 64 + m * 16 + lk * 4;
    int prow[4];
#pragma unroll
    for (int q = 0; q < 4; ++q)
      prow[q] = perm[m_base + rb + q];
#pragma unroll
    for (int n = 0; n < 4; ++n){
      int col = n0 + wn * 64 + n * 16 + lrow;
      fx4 v = acc[m][n];
#pragma unroll
      for (int q = 0; q < 4; ++q)
        if (prow[q] >= 0)
          out[(size_t)prow[q] * DOUT + col] = v[q] + bcol[n];
    }
  }
#undef KSTEP
#undef STGA
#undef STGB
}

extern "C" void kernel_launch(void* const* d_in, const int* in_sizes, int n_in,
                              void* d_out, int out_size, void* d_ws, size_t ws_size,
                              hipStream_t stream) {
  const float* xs      = (const float*)d_in[0];
  const float* W       = (const float*)d_in[1];
  const float* b       = (const float*)d_in[2];
  const int*   mxs     = (const int*)d_in[3];
  const int*   actions = (const int*)d_in[4];
  float* out = (float*)d_out;

  int*   perm = (int*)d_ws;                                   // GROWS ints
  int*   meta = (int*)((char*)d_ws + 40960);                  // [0..7] cursors, [16]=nslots, [17+]=expert
  short* Wt   = (short*)((char*)d_ws + 65536);                // 64 MB bf16 W^T
  short* xp   = (short*)((char*)d_ws + 65536 + (size_t)NEXP * DIN * DOUT * 2); // 37.75 MB

  hipLaunchKernelGGL(prep_count, dim3(1), dim3(1024), 0, stream, actions, perm, meta);
  hipLaunchKernelGGL(prep_scatter, dim3(32), dim3(256), 0, stream, actions, mxs, perm, meta, out);
  hipLaunchKernelGGL(gatherx_kernel, dim3(GROWS), dim3(256), 0, stream, xs, perm, xp);
  hipLaunchKernelGGL(transw_kernel, dim3(DOUT/64, DIN/64, NEXP), dim3(256), 0, stream, W, Wt);
  hipLaunchKernelGGL(moe_gemm_kernel, dim3(NSLOT * 8), dim3(512), 0, stream,
                     xp, Wt, b, perm, meta, out);
}

// Round 6
// 266.210 us; speedup vs baseline: 1.0677x; 1.0677x over previous
//
#include <hip/hip_runtime.h>
#include <hip/hip_bf16.h>
#include <stdint.h>

#define BATCH 8192
#define GROWS 9216          // >= 8192 + 7*127 padded rows
#define DIN   2048
#define DOUT  2048
#define NEXP  8
#define BM    128
#define BN    128
#define BK    32
#define NT    (DIN / BK)    // 64 K-tiles
#define NSLOT 72
// LDS: A slots 3 x 8192 at 0; B slots 3 x 8192 at 24576; total 49152 -> 3 blocks/CU
#define AS0 0
#define AS1 8192
#define AS2 16384
#define BS0 24576
#define BS1 32768
#define BS2 40960

typedef __attribute__((ext_vector_type(4))) float fx4;
typedef __attribute__((ext_vector_type(8))) short sx8;

__device__ __forceinline__ short f2b(float x){
  unsigned u = __float_as_uint(x);
  u = u + 0x7FFFu + ((u >> 16) & 1u);   // round-to-nearest-even
  return (short)(u >> 16);
}

__device__ __forceinline__ void gload16(const void* g, void* l){
  __builtin_amdgcn_global_load_lds(
      (const __attribute__((address_space(1))) unsigned int*)g,
      (__attribute__((address_space(3))) unsigned int*)l, 16, 0, 0);
}

// ---- pass 1: counts, offsets, slot->expert LUT, perm = -1 ----
__global__ void prep_count(const int* __restrict__ actions, int* __restrict__ perm,
                           int* __restrict__ meta){
  __shared__ int cnt[NEXP];
  int t = threadIdx.x;   // 1024
  if (t < NEXP) cnt[t] = 0;
  for (int i = t; i < GROWS; i += 1024) perm[i] = -1;
  __syncthreads();
  for (int i = t; i < BATCH; i += 1024) atomicAdd(&cnt[actions[i]], 1);
  __syncthreads();
  if (t == 0){
    int s = 0, slot = 0;
    for (int e = 0; e < NEXP; ++e){
      meta[e] = s;                          // running scatter cursor (global)
      int ns = (cnt[e] + BM - 1) / BM;
      for (int q = 0; q < ns; ++q) meta[17 + slot++] = e;
      s += ns * BM;
    }
    meta[16] = slot;
  }
}

// ---- pass 2: scatter perm (32 blocks) + metadata tail ----
__global__ void prep_scatter(const int* __restrict__ actions, const int* __restrict__ mxs,
                             int* __restrict__ perm, int* __restrict__ meta,
                             float* __restrict__ out){
  int i = blockIdx.x * 256 + threadIdx.x;
  if (i < BATCH){
    int e = actions[i];
    int p = atomicAdd(&meta[e], 1);
    perm[p] = i;
    out[(size_t)BATCH * DOUT + i]         = (float)mxs[i];
    out[(size_t)BATCH * DOUT + BATCH + i] = (float)actions[i];
  }
}

// ---- gather + convert: xp[i][k] = bf16(xs[perm[i]][k]); pad rows -> 0 ----
__global__ void gatherx_kernel(const float* __restrict__ xs, const int* __restrict__ perm,
                               short* __restrict__ xp){
  int i = blockIdx.x;
  int t = threadIdx.x;
  short v[8];
  int p = perm[i];
  if (p >= 0){
    const fx4* src = (const fx4*)(xs + (size_t)p * DIN + t * 8);
    fx4 a = src[0], b2 = src[1];
    v[0]=f2b(a.x); v[1]=f2b(a.y); v[2]=f2b(a.z); v[3]=f2b(a.w);
    v[4]=f2b(b2.x); v[5]=f2b(b2.y); v[6]=f2b(b2.z); v[7]=f2b(b2.w);
  } else {
#pragma unroll
    for (int j = 0; j < 8; ++j) v[j] = 0;
  }
  *(sx8*)(xp + (size_t)i * DIN + t * 8) = *(const sx8*)v;
}

// ---- W[e][k][n] f32 -> Wt[e][n][k] bf16 ----
__global__ void transw_kernel(const float* __restrict__ W, short* __restrict__ Wt){
  __shared__ float tile[64][69];
  int e  = blockIdx.z;
  int n0 = blockIdx.x * 64;
  int k0 = blockIdx.y * 64;
  const float* Wp = W + (size_t)e * DIN * DOUT + (size_t)k0 * DOUT + n0;
  int t = threadIdx.x;   // 256
#pragma unroll
  for (int it = 0; it < 4; ++it){
    int r = it * 16 + (t >> 4);
    int c = (t & 15) * 4;
    fx4 v = *(const fx4*)(Wp + (size_t)r * DOUT + c);
    tile[r][c] = v.x; tile[r][c+1] = v.y; tile[r][c+2] = v.z; tile[r][c+3] = v.w;
  }
  __syncthreads();
  int n  = t >> 2;
  int kc = (t & 3) * 16;
  short vv[16];
#pragma unroll
  for (int j = 0; j < 16; ++j) vv[j] = f2b(tile[kc + j][n]);
  short* dst = Wt + (size_t)e * DOUT * DIN + (size_t)(n0 + n) * DIN + k0 + kc;
  *(sx8*)dst       = *(const sx8*)vv;
  *(sx8*)(dst + 8) = *(const sx8*)(vv + 8);
}

// ---- grouped GEMM: 128x128xBK32, 4 waves, triple-buffer, vmcnt(4), 3 blocks/CU ----
__global__ __launch_bounds__(256, 3)
void moe_gemm_kernel(const short* __restrict__ xp, const short* __restrict__ Wt,
                     const float* __restrict__ bias, const int* __restrict__ perm,
                     const int* __restrict__ meta, float* __restrict__ out){
  __shared__ char lds[49152];

  int F = blockIdx.x;               // slot*16 + nb
  int slot = F >> 4, nb = F & 15;
  if (slot >= meta[16]) return;
  int e      = meta[17 + slot];
  int m_base = slot * BM;
  int n0     = nb * BN;

  int t    = threadIdx.x;
  int wid  = t >> 6;
  int l    = t & 63;
  int wm   = wid & 1;               // 2 wave rows
  int wn   = wid >> 1;              // 2 wave cols
  int lrow = l & 15;
  int kg   = l >> 4;                // 0..3

  // staging: chunks c = t and t+256 of [lk(4)][row(128)][16B]; c=t -> linear lds pos
  int srow = t & 127;
  int slk  = t >> 7;                // 0 or 1 (second chunk = slk+2 -> +32B in K)
  const char* ag = (const char*)xp + (size_t)(m_base + srow) * (DIN * 2) + slk * 16;
  const char* bg = (const char*)Wt + (size_t)e * ((size_t)DOUT * DIN * 2)
                                   + (size_t)(n0 + srow) * (DIN * 2) + slk * 16;

  // fragment read addrs: [kg][row][16B] -> conflict-free
  int addrA = kg * 2048 + (wm * 64 + lrow) * 16;
  int addrB = kg * 2048 + (wn * 64 + lrow) * 16;

  fx4 acc[4][4];
#pragma unroll
  for (int m = 0; m < 4; ++m)
#pragma unroll
    for (int n = 0; n < 4; ++n)
      acc[m][n] = (fx4){0.f, 0.f, 0.f, 0.f};

  float bcol[4];
#pragma unroll
  for (int n = 0; n < 4; ++n)
    bcol[n] = bias[(size_t)e * DOUT + n0 + wn * 64 + n * 16 + lrow];

#define STG(KT, SA, SB) do{ \
    gload16(ag + (size_t)(KT) * 64,      lds + (SA) + (t << 4)); \
    gload16(ag + (size_t)(KT) * 64 + 32, lds + (SA) + (t << 4) + 4096); \
    gload16(bg + (size_t)(KT) * 64,      lds + (SB) + (t << 4)); \
    gload16(bg + (size_t)(KT) * 64 + 32, lds + (SB) + (t << 4) + 4096); \
  }while(0)

#define KSTEP(CA, CB, SA, SB, KT, DOSTG, VM) do{ \
    if (DOSTG) STG((KT) + 2, SA, SB); \
    sx8 af[4], bf[4]; \
    _Pragma("unroll") for (int m = 0; m < 4; ++m) \
      af[m] = *(const sx8*)(lds + (CA) + addrA + m * 256); \
    _Pragma("unroll") for (int n = 0; n < 4; ++n) \
      bf[n] = *(const sx8*)(lds + (CB) + addrB + n * 256); \
    __builtin_amdgcn_s_setprio(1); \
    _Pragma("unroll") for (int m = 0; m < 4; ++m) \
    _Pragma("unroll") for (int n = 0; n < 4; ++n) \
      acc[m][n] = __builtin_amdgcn_mfma_f32_16x16x32_bf16(af[m], bf[n], acc[m][n], 0, 0, 0); \
    __builtin_amdgcn_s_setprio(0); \
    asm volatile("s_waitcnt vmcnt(" #VM ")" ::: "memory"); \
    __builtin_amdgcn_s_barrier(); \
    asm volatile("" ::: "memory"); \
  }while(0)

  // prologue: stage tiles 0,1 ; wait tile 0 (4 of 8 loads)
  STG(0, AS0, BS0);
  STG(1, AS1, BS1);
  asm volatile("s_waitcnt vmcnt(4)" ::: "memory");
  __builtin_amdgcn_s_barrier();
  asm volatile("" ::: "memory");

  for (int kt = 0; kt < 60; kt += 3){
    KSTEP(AS0, BS0, AS2, BS2, kt + 0, 1, 4);
    KSTEP(AS1, BS1, AS0, BS0, kt + 1, 1, 4);
    KSTEP(AS2, BS2, AS1, BS1, kt + 2, 1, 4);
  }
  KSTEP(AS0, BS0, AS2, BS2, 60, 1, 4);   // stages 62
  KSTEP(AS1, BS1, AS0, BS0, 61, 1, 4);   // stages 63
  KSTEP(AS2, BS2, AS0, BS0, 62, 0, 0);   // drain: tile 63 landed
  // step 63: compute only
  {
    sx8 af[4], bf[4];
#pragma unroll
    for (int m = 0; m < 4; ++m) af[m] = *(const sx8*)(lds + AS0 + addrA + m * 256);
#pragma unroll
    for (int n = 0; n < 4; ++n) bf[n] = *(const sx8*)(lds + BS0 + addrB + n * 256);
#pragma unroll
    for (int m = 0; m < 4; ++m)
#pragma unroll
      for (int n = 0; n < 4; ++n)
        acc[m][n] = __builtin_amdgcn_mfma_f32_16x16x32_bf16(af[m], bf[n], acc[m][n], 0, 0, 0);
  }

  // epilogue: scatter rows via perm, add bias
#pragma unroll
  for (int m = 0; m < 4; ++m){
    int rb = wm * 64 + m * 16 + kg * 4;
    int prow[4];
#pragma unroll
    for (int q = 0; q < 4; ++q)
      prow[q] = perm[m_base + rb + q];
#pragma unroll
    for (int n = 0; n < 4; ++n){
      int col = n0 + wn * 64 + n * 16 + lrow;
      fx4 v = acc[m][n];
#pragma unroll
      for (int q = 0; q < 4; ++q)
        if (prow[q] >= 0)
          out[(size_t)prow[q] * DOUT + col] = v[q] + bcol[n];
    }
  }
#undef KSTEP
#undef STG
}

extern "C" void kernel_launch(void* const* d_in, const int* in_sizes, int n_in,
                              void* d_out, int out_size, void* d_ws, size_t ws_size,
                              hipStream_t stream) {
  const float* xs      = (const float*)d_in[0];
  const float* W       = (const float*)d_in[1];
  const float* b       = (const float*)d_in[2];
  const int*   mxs     = (const int*)d_in[3];
  const int*   actions = (const int*)d_in[4];
  float* out = (float*)d_out;

  int*   perm = (int*)d_ws;                                   // GROWS ints
  int*   meta = (int*)((char*)d_ws + 40960);                  // [0..7] cursors, [16]=nslots, [17+]=expert
  short* Wt   = (short*)((char*)d_ws + 65536);                // 64 MB bf16 W^T
  short* xp   = (short*)((char*)d_ws + 65536 + (size_t)NEXP * DIN * DOUT * 2); // 37.75 MB

  hipLaunchKernelGGL(prep_count, dim3(1), dim3(1024), 0, stream, actions, perm, meta);
  hipLaunchKernelGGL(prep_scatter, dim3(32), dim3(256), 0, stream, actions, mxs, perm, meta, out);
  hipLaunchKernelGGL(gatherx_kernel, dim3(GROWS), dim3(256), 0, stream, xs, perm, xp);
  hipLaunchKernelGGL(transw_kernel, dim3(DOUT/64, DIN/64, NEXP), dim3(256), 0, stream, W, Wt);
  hipLaunchKernelGGL(moe_gemm_kernel, dim3(NSLOT * 16), dim3(256), 0, stream,
                     xp, Wt, b, perm, meta, out);
}

// Round 7
// 262.171 us; speedup vs baseline: 1.0841x; 1.0154x over previous
//
#include <hip/hip_runtime.h>
#include <hip/hip_bf16.h>
#include <stdint.h>

#define BATCH 8192
#define GROWS 10240         // >= 8192 + 8*255, 256-aligned segments
#define DIN   2048
#define DOUT  2048
#define NEXP  8
#define BM    256
#define BN    256
#define BK    64
#define NT    (DIN / BK)    // 32 K-tiles
#define NSLOT 40            // max 256-row slots

typedef __attribute__((ext_vector_type(4))) float fx4;
typedef __attribute__((ext_vector_type(8))) short sx8;

__device__ __forceinline__ short f2b(float x){
  unsigned u = __float_as_uint(x);
  u = u + 0x7FFFu + ((u >> 16) & 1u);   // round-to-nearest-even
  return (short)(u >> 16);
}

__device__ __forceinline__ void gload16(const void* g, void* l){
  __builtin_amdgcn_global_load_lds(
      (const __attribute__((address_space(1))) unsigned int*)g,
      (__attribute__((address_space(3))) unsigned int*)l, 16, 0, 0);
}

// ---- pass 1: counts, 256-aligned offsets, slot->expert LUT, perm = -1 ----
__global__ void prep_count(const int* __restrict__ actions, int* __restrict__ perm,
                           int* __restrict__ meta){
  __shared__ int cnt[NEXP];
  int t = threadIdx.x;   // 1024
  if (t < NEXP) cnt[t] = 0;
  for (int i = t; i < GROWS; i += 1024) perm[i] = -1;
  __syncthreads();
  for (int i = t; i < BATCH; i += 1024) atomicAdd(&cnt[actions[i]], 1);
  __syncthreads();
  if (t == 0){
    int s = 0, slot = 0;
    for (int e = 0; e < NEXP; ++e){
      meta[e] = s;                          // running scatter cursor (global)
      int ns = (cnt[e] + BM - 1) / BM;
      for (int q = 0; q < ns; ++q) meta[17 + slot++] = e;
      s += ns * BM;
    }
    meta[16] = slot;
  }
}

// ---- pass 2: scatter perm (32 blocks) + metadata tail ----
__global__ void prep_scatter(const int* __restrict__ actions, const int* __restrict__ mxs,
                             int* __restrict__ perm, int* __restrict__ meta,
                             float* __restrict__ out){
  int i = blockIdx.x * 256 + threadIdx.x;
  if (i < BATCH){
    int e = actions[i];
    int p = atomicAdd(&meta[e], 1);
    perm[p] = i;
    out[(size_t)BATCH * DOUT + i]         = (float)mxs[i];
    out[(size_t)BATCH * DOUT + BATCH + i] = (float)actions[i];
  }
}

// ---- gather + convert: xp[i][k] = bf16(xs[perm[i]][k]); pad rows -> 0 ----
__global__ void gatherx_kernel(const float* __restrict__ xs, const int* __restrict__ perm,
                               short* __restrict__ xp){
  int i = blockIdx.x;
  int t = threadIdx.x;
  short v[8];
  int p = perm[i];
  if (p >= 0){
    const fx4* src = (const fx4*)(xs + (size_t)p * DIN + t * 8);
    fx4 a = src[0], b2 = src[1];
    v[0]=f2b(a.x); v[1]=f2b(a.y); v[2]=f2b(a.z); v[3]=f2b(a.w);
    v[4]=f2b(b2.x); v[5]=f2b(b2.y); v[6]=f2b(b2.z); v[7]=f2b(b2.w);
  } else {
#pragma unroll
    for (int j = 0; j < 8; ++j) v[j] = 0;
  }
  *(sx8*)(xp + (size_t)i * DIN + t * 8) = *(const sx8*)v;
}

// ---- W[e][k][n] f32 -> Wt[e][n][k] bf16 ----
__global__ void transw_kernel(const float* __restrict__ W, short* __restrict__ Wt){
  __shared__ float tile[64][69];
  int e  = blockIdx.z;
  int n0 = blockIdx.x * 64;
  int k0 = blockIdx.y * 64;
  const float* Wp = W + (size_t)e * DIN * DOUT + (size_t)k0 * DOUT + n0;
  int t = threadIdx.x;   // 256
#pragma unroll
  for (int it = 0; it < 4; ++it){
    int r = it * 16 + (t >> 4);
    int c = (t & 15) * 4;
    fx4 v = *(const fx4*)(Wp + (size_t)r * DOUT + c);
    tile[r][c] = v.x; tile[r][c+1] = v.y; tile[r][c+2] = v.z; tile[r][c+3] = v.w;
  }
  __syncthreads();
  int n  = t >> 2;
  int kc = (t & 3) * 16;
  short vv[16];
#pragma unroll
  for (int j = 0; j < 16; ++j) vv[j] = f2b(tile[kc + j][n]);
  short* dst = Wt + (size_t)e * DOUT * DIN + (size_t)(n0 + n) * DIN + k0 + kc;
  *(sx8*)dst       = *(const sx8*)vv;
  *(sx8*)(dst + 8) = *(const sx8*)(vv + 8);
}

// ---- grouped GEMM: 256x256xBK64, 8 waves, 8-phase-per-2-tiles, vmcnt(6) ----
__global__ __launch_bounds__(512, 2)
void moe_gemm_kernel(const short* __restrict__ xp, const short* __restrict__ Wt,
                     const float* __restrict__ bias, const int* __restrict__ perm,
                     const int* __restrict__ meta, float* __restrict__ out){
  extern __shared__ char lds[];   // 2 x 64KB: per buf {A 32KB [c8][row256][16B], B 32KB}

  int F = blockIdx.x;
  int nslots = meta[16];
  int x = F & 7, bi = F >> 3;
  if (bi >= nslots) return;
  int J    = x * nslots + bi;     // XCD x gets contiguous slot chunk
  int slot = J >> 3, nb = J & 7;
  int e      = meta[17 + slot];
  int m_base = slot * BM;
  int n0     = nb * BN;

  int t    = threadIdx.x;
  int wid  = t >> 6;
  int l    = t & 63;
  int wm   = wid >> 2;            // 2 wave rows (128 rows each)
  int wn   = wid & 3;             // 4 wave cols (64 cols each)
  int lrow = l & 15;
  int lk   = l >> 4;

  // staging: thread t covers row r, chunk ci / ci+2 of a k-half
  int r  = t & 255;
  int ci = t >> 8;
  const char* agb = (const char*)xp + (size_t)(m_base + r) * (DIN * 2);
  const char* bgb = (const char*)Wt + (size_t)e * ((size_t)DOUT * DIN * 2)
                                    + (size_t)(n0 + r) * (DIN * 2);
  int adst = ci * 4096 + r * 16;
  int bdst = 32768 + ci * 4096 + r * 16;

#define STGA(KT, KK) do{ int _b = (((KT) & 1) << 16) + ((KK) << 14) + adst; \
    gload16(agb + (KT) * 128 + (((KK) * 4 + ci)    ) * 16, lds + _b); \
    gload16(agb + (KT) * 128 + (((KK) * 4 + ci + 2)) * 16, lds + _b + 8192); }while(0)
#define STGB(KT, KK) do{ int _b = (((KT) & 1) << 16) + ((KK) << 14) + bdst; \
    gload16(bgb + (KT) * 128 + (((KK) * 4 + ci)    ) * 16, lds + _b); \
    gload16(bgb + (KT) * 128 + (((KK) * 4 + ci + 2)) * 16, lds + _b + 8192); }while(0)

  int aoffs = (wm * 128 + lrow) * 16;          // + mf*256 + (kk*4+lk)*4096 + buf
  int boffs = 32768 + (wn * 64 + lrow) * 16;   // + nf*256 + (kk*4+lk)*4096 + buf

  fx4 acc[8][4];
#pragma unroll
  for (int m = 0; m < 8; ++m)
#pragma unroll
    for (int n = 0; n < 4; ++n)
      acc[m][n] = (fx4){0.f, 0.f, 0.f, 0.f};
  sx8 bf[4];

  float bcol[4];
#pragma unroll
  for (int n = 0; n < 4; ++n)
    bcol[n] = bias[(size_t)e * DOUT + n0 + wn * 64 + n * 16 + lrow];

// phase: {ds_read frags | stage one half | [vmcnt] | barrier | 16 MFMA | barrier}
#define PHASE(XB, MH, KK, RB, STGST, VMN) do{ \
    sx8 af[4]; \
    if (RB){ _Pragma("unroll") for (int nf = 0; nf < 4; ++nf) \
        bf[nf] = *(const sx8*)(lds + (XB) + (((KK)*4+lk) << 12) + boffs + nf * 256); } \
    _Pragma("unroll") for (int q = 0; q < 4; ++q) \
        af[q] = *(const sx8*)(lds + (XB) + (((KK)*4+lk) << 12) + aoffs + ((MH)*4+q) * 256); \
    STGST; \
    if ((VMN) == 6) asm volatile("s_waitcnt vmcnt(6)" ::: "memory"); \
    if ((VMN) == 0) asm volatile("s_waitcnt vmcnt(0)" ::: "memory"); \
    __builtin_amdgcn_s_barrier(); asm volatile("" ::: "memory"); \
    __builtin_amdgcn_s_setprio(1); \
    _Pragma("unroll") for (int q = 0; q < 4; ++q) \
    _Pragma("unroll") for (int nf = 0; nf < 4; ++nf) \
        acc[(MH)*4+q][nf] = __builtin_amdgcn_mfma_f32_16x16x32_bf16(af[q], bf[nf], acc[(MH)*4+q][nf], 0, 0, 0); \
    __builtin_amdgcn_s_setprio(0); \
    __builtin_amdgcn_s_barrier(); asm volatile("" ::: "memory"); \
  }while(0)

  // prologue: tile0 full (8), tile1 minus A-k1 (6) -- order matches steady FIFO
  STGA(0, 0); STGA(0, 1); STGB(0, 0); STGB(0, 1);
  STGB(1, 0); STGA(1, 0); STGB(1, 1);
  asm volatile("s_waitcnt vmcnt(6)" ::: "memory");   // tile0 landed
  __builtin_amdgcn_s_barrier();
  asm volatile("" ::: "memory");

  for (int kt = 0; kt < NT - 2; ++kt){
    int XB = (kt & 1) << 16;
    PHASE(XB, 0, 0, 1, STGA(kt + 1, 1), -1);   // A-k1 of kt+1 (freed kt-1 P3)
    PHASE(XB, 1, 0, 0, STGB(kt + 2, 0), -1);   // B-k0 freed at P0
    PHASE(XB, 0, 1, 1, STGA(kt + 2, 0), -1);   // A-k0 freed at P1
    PHASE(XB, 1, 1, 0, STGB(kt + 2, 1),  6);   // B-k1 freed at P2; tile kt+1 landed
  }
  { int kt = NT - 2; int XB = (kt & 1) << 16;
    PHASE(XB, 0, 0, 1, STGA(kt + 1, 1), -1);   // completes tile NT-1
    PHASE(XB, 1, 0, 0, (void)0, -1);
    PHASE(XB, 0, 1, 1, (void)0, -1);
    PHASE(XB, 1, 1, 0, (void)0,  0);           // drain: tile NT-1 landed
  }
  { int XB = ((NT - 1) & 1) << 16;
    PHASE(XB, 0, 0, 1, (void)0, -1);
    PHASE(XB, 1, 0, 0, (void)0, -1);
    PHASE(XB, 0, 1, 1, (void)0, -1);
    PHASE(XB, 1, 1, 0, (void)0, -1);
  }

  // epilogue: scatter rows via perm, add bias
#pragma unroll
  for (int mf = 0; mf < 8; ++mf){
    int rb = m_base + wm * 128 + mf * 16 + lk * 4;
    int prow[4];
#pragma unroll
    for (int q = 0; q < 4; ++q)
      prow[q] = perm[rb + q];
#pragma unroll
    for (int nf = 0; nf < 4; ++nf){
      int col = n0 + wn * 64 + nf * 16 + lrow;
      fx4 v = acc[mf][nf];
#pragma unroll
      for (int q = 0; q < 4; ++q)
        if (prow[q] >= 0)
          out[(size_t)prow[q] * DOUT + col] = v[q] + bcol[nf];
    }
  }
#undef PHASE
#undef STGA
#undef STGB
}

extern "C" void kernel_launch(void* const* d_in, const int* in_sizes, int n_in,
                              void* d_out, int out_size, void* d_ws, size_t ws_size,
                              hipStream_t stream) {
  const float* xs      = (const float*)d_in[0];
  const float* W       = (const float*)d_in[1];
  const float* b       = (const float*)d_in[2];
  const int*   mxs     = (const int*)d_in[3];
  const int*   actions = (const int*)d_in[4];
  float* out = (float*)d_out;

  int*   perm = (int*)d_ws;                                   // GROWS ints = 40960 B
  int*   meta = (int*)((char*)d_ws + 40960);                  // cursors + nslots + LUT
  short* Wt   = (short*)((char*)d_ws + 65536);                // 64 MB bf16 W^T
  short* xp   = (short*)((char*)d_ws + 65536 + (size_t)NEXP * DIN * DOUT * 2); // 40 MB

  hipLaunchKernelGGL(prep_count, dim3(1), dim3(1024), 0, stream, actions, perm, meta);
  hipLaunchKernelGGL(prep_scatter, dim3(32), dim3(256), 0, stream, actions, mxs, perm, meta, out);
  hipLaunchKernelGGL(gatherx_kernel, dim3(GROWS), dim3(256), 0, stream, xs, perm, xp);
  hipLaunchKernelGGL(transw_kernel, dim3(DOUT/64, DIN/64, NEXP), dim3(256), 0, stream, W, Wt);
  hipLaunchKernelGGL(moe_gemm_kernel, dim3(NSLOT * 8), dim3(512), 131072, stream,
                     xp, Wt, b, perm, meta, out);
}

// Round 8
// 209.872 us; speedup vs baseline: 1.3543x; 1.2492x over previous
//
#include <hip/hip_runtime.h>
#include <hip/hip_bf16.h>
#include <stdint.h>

#define BATCH 8192
#define GROWS 9216          // >= 8192 + 7*127 padded rows
#define DIN   2048
#define DOUT  2048
#define NEXP  8
#define BM    128
#define BN    256
#define BK    32
#define NT    (DIN / BK)    // 64 K-tiles
#define NSLOT 72
#define BUFSZ 24576         // per K-tile buffer: A 8K + B 16K
#define BOFF  8192          // B region offset within buffer

typedef __attribute__((ext_vector_type(4))) float fx4;
typedef __attribute__((ext_vector_type(8))) short sx8;

__device__ __forceinline__ short f2b(float x){
  unsigned u = __float_as_uint(x);
  u = u + 0x7FFFu + ((u >> 16) & 1u);   // round-to-nearest-even
  return (short)(u >> 16);
}

__device__ __forceinline__ void gload16(const void* g, void* l){
  __builtin_amdgcn_global_load_lds(
      (const __attribute__((address_space(1))) unsigned int*)g,
      (__attribute__((address_space(3))) unsigned int*)l, 16, 0, 0);
}

// ---- pass 1: counts, 128-aligned offsets, slot->expert LUT, perm=-1, work ctr ----
__global__ void prep_count(const int* __restrict__ actions, int* __restrict__ perm,
                           int* __restrict__ meta){
  __shared__ int cnt[NEXP];
  int t = threadIdx.x;   // 1024
  if (t < NEXP) cnt[t] = 0;
  for (int i = t; i < GROWS; i += 1024) perm[i] = -1;
  __syncthreads();
  for (int i = t; i < BATCH; i += 1024) atomicAdd(&cnt[actions[i]], 1);
  __syncthreads();
  if (t == 0){
    int s = 0, slot = 0;
    for (int e = 0; e < NEXP; ++e){
      meta[e] = s;                          // running scatter cursor (global)
      int ns = (cnt[e] + BM - 1) / BM;
      for (int q = 0; q < ns; ++q) meta[17 + slot++] = e;
      s += ns * BM;
    }
    meta[16] = slot;
    meta[15] = 0;                           // work-steal counter
  }
}

// ---- pass 2: scatter perm (32 blocks) + metadata tail ----
__global__ void prep_scatter(const int* __restrict__ actions, const int* __restrict__ mxs,
                             int* __restrict__ perm, int* __restrict__ meta,
                             float* __restrict__ out){
  int i = blockIdx.x * 256 + threadIdx.x;
  if (i < BATCH){
    int e = actions[i];
    int p = atomicAdd(&meta[e], 1);
    perm[p] = i;
    out[(size_t)BATCH * DOUT + i]         = (float)mxs[i];
    out[(size_t)BATCH * DOUT + BATCH + i] = (float)actions[i];
  }
}

// ---- gather + convert: xp[i][k] = bf16(xs[perm[i]][k]); pad rows -> 0 ----
__global__ void gatherx_kernel(const float* __restrict__ xs, const int* __restrict__ perm,
                               short* __restrict__ xp){
  int i = blockIdx.x;
  int t = threadIdx.x;
  short v[8];
  int p = perm[i];
  if (p >= 0){
    const fx4* src = (const fx4*)(xs + (size_t)p * DIN + t * 8);
    fx4 a = src[0], b2 = src[1];
    v[0]=f2b(a.x); v[1]=f2b(a.y); v[2]=f2b(a.z); v[3]=f2b(a.w);
    v[4]=f2b(b2.x); v[5]=f2b(b2.y); v[6]=f2b(b2.z); v[7]=f2b(b2.w);
  } else {
#pragma unroll
    for (int j = 0; j < 8; ++j) v[j] = 0;
  }
  *(sx8*)(xp + (size_t)i * DIN + t * 8) = *(const sx8*)v;
}

// ---- W[e][k][n] f32 -> Wt[e][n][k] bf16 ----
__global__ void transw_kernel(const float* __restrict__ W, short* __restrict__ Wt){
  __shared__ float tile[64][69];
  int e  = blockIdx.z;
  int n0 = blockIdx.x * 64;
  int k0 = blockIdx.y * 64;
  const float* Wp = W + (size_t)e * DIN * DOUT + (size_t)k0 * DOUT + n0;
  int t = threadIdx.x;   // 256
#pragma unroll
  for (int it = 0; it < 4; ++it){
    int r = it * 16 + (t >> 4);
    int c = (t & 15) * 4;
    fx4 v = *(const fx4*)(Wp + (size_t)r * DOUT + c);
    tile[r][c] = v.x; tile[r][c+1] = v.y; tile[r][c+2] = v.z; tile[r][c+3] = v.w;
  }
  __syncthreads();
  int n  = t >> 2;
  int kc = (t & 3) * 16;
  short vv[16];
#pragma unroll
  for (int j = 0; j < 16; ++j) vv[j] = f2b(tile[kc + j][n]);
  short* dst = Wt + (size_t)e * DOUT * DIN + (size_t)(n0 + n) * DIN + k0 + kc;
  *(sx8*)dst       = *(const sx8*)vv;
  *(sx8*)(dst + 8) = *(const sx8*)(vv + 8);
}

// ---- grouped GEMM: 128x256xBK32, triple-buffer, vmcnt(3)/step, work-stealing ----
__global__ __launch_bounds__(512, 4)
void moe_gemm_kernel(const short* __restrict__ xp, const short* __restrict__ Wt,
                     const float* __restrict__ bias, const int* __restrict__ perm,
                     int* __restrict__ meta, float* __restrict__ out){
  __shared__ char lds[3 * BUFSZ];   // 72 KB -> 2 blocks/CU
  __shared__ int s_item;

  int nitems = meta[16] * 8;

  int t    = threadIdx.x;
  int wid  = t >> 6;
  int l    = t & 63;
  int wm   = wid & 1;               // 2 wave rows
  int wn   = wid >> 1;              // 4 wave cols
  int lrow = l & 15;
  int lk   = l >> 4;

  // staging thread geometry (item-independent parts)
  int srow = ((t >> 3) << 1) | ((t >> 2) & 1);
  int schk = (t & 3) ^ ((t >> 3) & 3);
  int ldst = t * 16;

  // fragment read addresses (same involution as staging)
  int arow = wm * 64 + lrow;
  int aline = arow >> 1;
  int addrA = aline * 128 + (arow & 1) * 64 + ((lk ^ (aline & 3)) << 4);
  int brow = wn * 64 + lrow;
  int bline = brow >> 1;
  int addrB = BOFF + bline * 128 + (brow & 1) * 64 + ((lk ^ (bline & 3)) << 4);

  for (;;){
    if (t == 0) s_item = atomicAdd(&meta[15], 1);
    __syncthreads();                 // broadcast item + drain prior item's LDS reads
    int item = s_item;
    if (item >= nitems) break;

    int slot = item >> 3, nb = item & 7;
    int e      = meta[17 + slot];
    int m_base = slot * BM;
    int n0     = nb * BN;

    const char* ag  = (const char*)xp + ((size_t)(m_base + srow) * DIN + schk * 8) * 2;
    const char* bg0 = (const char*)Wt + (((size_t)e * DOUT + n0 + srow) * DIN + schk * 8) * 2;
    const char* bg1 = bg0 + (size_t)128 * DIN * 2;

#define STAGE(kt, BASE) do{ \
    gload16(ag  + (size_t)(kt) * 64, lds + (BASE) + ldst); \
    gload16(bg0 + (size_t)(kt) * 64, lds + (BASE) + BOFF + ldst); \
    gload16(bg1 + (size_t)(kt) * 64, lds + (BASE) + BOFF + 8192 + ldst); \
  }while(0)

    fx4 acc[4][4];
#pragma unroll
    for (int m = 0; m < 4; ++m)
#pragma unroll
      for (int n = 0; n < 4; ++n)
        acc[m][n] = (fx4){0.f, 0.f, 0.f, 0.f};

    float bcol[4];
#pragma unroll
    for (int n = 0; n < 4; ++n)
      bcol[n] = bias[(size_t)e * DOUT + n0 + wn * 64 + n * 16 + lrow];

#define KSTEP(CB, SB, DOSTG, kt) do{ \
    sx8 af[4], bf[4]; \
    _Pragma("unroll") for (int m = 0; m < 4; ++m) \
      af[m] = *(const sx8*)(lds + (CB) + addrA + m * 1024); \
    _Pragma("unroll") for (int n = 0; n < 4; ++n) \
      bf[n] = *(const sx8*)(lds + (CB) + addrB + n * 1024); \
    if (DOSTG) STAGE((kt) + 2, SB); \
    __builtin_amdgcn_s_setprio(1); \
    _Pragma("unroll") for (int m = 0; m < 4; ++m) \
    _Pragma("unroll") for (int n = 0; n < 4; ++n) \
      acc[m][n] = __builtin_amdgcn_mfma_f32_16x16x32_bf16(af[m], bf[n], acc[m][n], 0, 0, 0); \
    __builtin_amdgcn_s_setprio(0); \
    if (DOSTG) asm volatile("s_waitcnt vmcnt(3)" ::: "memory"); \
    else       asm volatile("s_waitcnt vmcnt(0)" ::: "memory"); \
    __builtin_amdgcn_s_barrier(); \
    asm volatile("" ::: "memory"); \
  }while(0)

    // prologue: stage tiles 0,1 ; wait tile 0 (3 of 6 loads)
    STAGE(0, 0);
    STAGE(1, BUFSZ);
    asm volatile("s_waitcnt vmcnt(3)" ::: "memory");
    __builtin_amdgcn_s_barrier();
    asm volatile("" ::: "memory");

    for (int kt = 0; kt < 60; kt += 3){
      KSTEP(0,         2*BUFSZ, 1, kt);
      KSTEP(BUFSZ,     0,       1, kt + 1);
      KSTEP(2*BUFSZ,   BUFSZ,   1, kt + 2);
    }
    KSTEP(0,       2*BUFSZ, 1, 60);   // stages 62 -> buf2
    KSTEP(BUFSZ,   0,       1, 61);   // stages 63 -> buf0
    KSTEP(2*BUFSZ, 0,       0, 62);   // vmcnt(0): tile 63 landed
    // step 63: compute only (loop-top __syncthreads protects these LDS reads)
    {
      sx8 af[4], bf[4];
#pragma unroll
      for (int m = 0; m < 4; ++m) af[m] = *(const sx8*)(lds + addrA + m * 1024);
#pragma unroll
      for (int n = 0; n < 4; ++n) bf[n] = *(const sx8*)(lds + addrB + n * 1024);
#pragma unroll
      for (int m = 0; m < 4; ++m)
#pragma unroll
        for (int n = 0; n < 4; ++n)
          acc[m][n] = __builtin_amdgcn_mfma_f32_16x16x32_bf16(af[m], bf[n], acc[m][n], 0, 0, 0);
    }

    // epilogue: scatter rows via perm, add bias
#pragma unroll
    for (int m = 0; m < 4; ++m){
      int rb = wm * 64 + m * 16 + lk * 4;
      int prow[4];
#pragma unroll
      for (int q = 0; q < 4; ++q)
        prow[q] = perm[m_base + rb + q];
#pragma unroll
      for (int n = 0; n < 4; ++n){
        int col = n0 + wn * 64 + n * 16 + lrow;
        fx4 v = acc[m][n];
#pragma unroll
        for (int q = 0; q < 4; ++q)
          if (prow[q] >= 0)
            out[(size_t)prow[q] * DOUT + col] = v[q] + bcol[n];
      }
    }
#undef KSTEP
#undef STAGE
  }
}

extern "C" void kernel_launch(void* const* d_in, const int* in_sizes, int n_in,
                              void* d_out, int out_size, void* d_ws, size_t ws_size,
                              hipStream_t stream) {
  const float* xs      = (const float*)d_in[0];
  const float* W       = (const float*)d_in[1];
  const float* b       = (const float*)d_in[2];
  const int*   mxs     = (const int*)d_in[3];
  const int*   actions = (const int*)d_in[4];
  float* out = (float*)d_out;

  int*   perm = (int*)d_ws;                                   // GROWS ints
  int*   meta = (int*)((char*)d_ws + 40960);                  // cursors, ctr, nslots, LUT
  short* Wt   = (short*)((char*)d_ws + 65536);                // 32 MB bf16 W^T
  short* xp   = (short*)((char*)d_ws + 65536 + (size_t)NEXP * DIN * DOUT * 2); // 37.75 MB

  hipLaunchKernelGGL(prep_count, dim3(1), dim3(1024), 0, stream, actions, perm, meta);
  hipLaunchKernelGGL(prep_scatter, dim3(32), dim3(256), 0, stream, actions, mxs, perm, meta, out);
  hipLaunchKernelGGL(gatherx_kernel, dim3(GROWS), dim3(256), 0, stream, xs, perm, xp);
  hipLaunchKernelGGL(transw_kernel, dim3(DOUT/64, DIN/64, NEXP), dim3(256), 0, stream, W, Wt);
  hipLaunchKernelGGL(moe_gemm_kernel, dim3(512), dim3(512), 0, stream,
                     xp, Wt, b, perm, meta, out);
}